// Round 6
// baseline (859.439 us; speedup 1.0000x reference)
//
#include <hip/hip_runtime.h>

// GeneralizedInteractionNet on MI355X (gfx950). R15: tile-level software
// pipeline inside compute (issue MFMA(t) before combine(t-1)); no setprio.
//
// Per layer:  M[n,D,d] = W[n,D,d]*h[n,d]
//   GEMM1: C[b,i,D] = sum_d Bi[b,i,d] * M[n,D,d]
//   GEMM2: R[b,i,D] = sum_f AT[n,i,f] * B0T[b,D,f]^T
//   out[b,n,D] = sum_i C[b,i,D]*R[b,i,D]
// i padded 40->64 (2 row tiles of 32); f padded 40->48 (3 K-steps of 16).
//
// History:
//  R9 (263us): L2-direct frags, MfmaUtil 39%.  R10 (361us): failed reg-dbuf.
//  R11 (261us): 4-chain interleave = noise.
//  R12 (235us): LDS staging + XCD grouping; FETCH 46->13.7MB, MfmaUtil 47%.
//  R13 (908us): launch_bounds(256,4) -> massive spill (R6/R8 mistake again).
//  R14 (240us): R13 at (256,2): layer 63.4us = R12. acc-zero kill + DMA
//    staging NEUTRAL; VALUBusy unchanged 26% -> zero-init was NOT the VALU
//    dominator. Additive pipes persist (MFMA 47 + VALU 26 + LDS ~ wall).
//  R15 theory: waves issue IN ORDER. Per tile, combine(t) reads acc regs of
//    the chain that just issued -> scoreboard stall ~MFMA latency, during
//    which the NEXT tile's independent MFMAs (later in program order) cannot
//    issue -> matrix pipe drains 8x per n. Both waves phase-locked -> no TLP
//    rescue. setprio intrinsics additionally FENCE the scheduler (unmodeled
//    side effects) from hoisting MFMAs across the combine. Fix: explicit
//    tile pipeline -- issue chain(t), then combine(t-1) (accs long retired);
//    two parity-indexed acc sets (unrolled -> static indexing); setprio gone.

typedef __bf16 bf16x8 __attribute__((ext_vector_type(8)));
typedef float  f32x16 __attribute__((ext_vector_type(16)));
typedef unsigned short us4 __attribute__((ext_vector_type(4)));

constexpr int BATCH = 2048;
constexpr int FDIM  = 40;
constexpr int DDIM  = 64;
constexpr int LAY   = 3;
constexpr int FPAD  = 48;   // f padding for B0T (3 K-steps of 16)
constexpr int APAD  = 56;   // AT row stride in ushorts (112B -> 4-way max)
constexpr int NSPL  = 4;    // n-loop split across 4 blocks
constexpr int NPB   = FDIM / NSPL;    // 10 n per block
constexpr int BPB   = 8;    // b per block (4 waves x b2=2)
constexpr int MSLAB = DDIM * DDIM;    // 4096 ushort per n (8 KB)
constexpr int ASLAB = DDIM * APAD;    // 3584 ushort per n (7 KB)

__device__ __forceinline__ unsigned short f2bf(float f) {
  union { float f; unsigned u; } v; v.f = f;
  unsigned r = v.u + 0x7fff + ((v.u >> 16) & 1);   // round-to-nearest-even
  return (unsigned short)(r >> 16);
}

__device__ __forceinline__ void dma16(unsigned short* lds, const unsigned short* g) {
  __builtin_amdgcn_global_load_lds(
      (const __attribute__((address_space(1))) unsigned int*)g,
      (__attribute__((address_space(3))) unsigned int*)lds, 16, 0, 0);
}

// Single prep launch, role by blockIdx.x:
//  blocks [0, BATCH):  B0b[b,f,d] = bf16(inputs); B0T[b,d,f48] via LDS transpose
//  blocks [BATCH, ..): Mswz (pre-swizzled W*h), ATp (alpha^T, stride-56, zero-pad)
__global__ __launch_bounds__(256) void prep_all(
    const float* __restrict__ inputs, const float* __restrict__ W,
    const float* __restrict__ h, const float* __restrict__ alpha,
    unsigned short* __restrict__ B0b, unsigned short* __restrict__ B0T,
    unsigned short* __restrict__ M, unsigned short* __restrict__ AT) {
  __shared__ float lds[FDIM][DDIM + 1];
  if (blockIdx.x < BATCH) {
    const int b = blockIdx.x;
    const float* src = inputs + (size_t)b * FDIM * DDIM;
    for (int cch = threadIdx.x; cch < FDIM * DDIM / 4; cch += 256) {
      float4 v = reinterpret_cast<const float4*>(src)[cch];
      int e = cch * 4;
      int f = e >> 6, d = e & 63;
      lds[f][d] = v.x; lds[f][d + 1] = v.y; lds[f][d + 2] = v.z; lds[f][d + 3] = v.w;
      us4 o = { f2bf(v.x), f2bf(v.y), f2bf(v.z), f2bf(v.w) };
      reinterpret_cast<us4*>(B0b + (size_t)b * FDIM * DDIM)[cch] = o;
    }
    __syncthreads();
    for (int cch = threadIdx.x; cch < DDIM * FPAD / 4; cch += 256) {
      int f4 = cch % (FPAD / 4);
      int d  = cch / (FPAD / 4);
      us4 o = {0, 0, 0, 0};
      if (f4 < FDIM / 4) {
        int f = f4 * 4;
        o[0] = f2bf(lds[f][d]);     o[1] = f2bf(lds[f + 1][d]);
        o[2] = f2bf(lds[f + 2][d]); o[3] = f2bf(lds[f + 3][d]);
      }
      reinterpret_cast<us4*>(B0T + (size_t)b * DDIM * FPAD)[cch] = o;
    }
    return;
  }
  int j = (blockIdx.x - BATCH) * 256 + threadIdx.x;
  const int nM4 = LAY * FDIM * MSLAB / 4;    // 122880
  const int nA4 = LAY * FDIM * ASLAB / 4;    // 107520
  if (j < nM4) {
    // Mswz linear pos e = row*64 + jc*8 + o holds M[ln][row][(jc^(row&7))*8+o]
    // so the layer's swizzled ds_read (chunk ^= c&7) lands on natural data.
    int e   = j * 4;
    int ln  = e >> 12;
    int row = (e >> 6) & 63;
    int jc  = (e >> 3) & 7;
    int o   = e & 7;                      // 0 or 4
    int ds  = ((jc ^ (row & 7)) << 3) + o;
    float4 wv = *reinterpret_cast<const float4*>(W + ((size_t)ln * 64 + row) * 64 + ds);
    float4 hv = *reinterpret_cast<const float4*>(h + (size_t)ln * 64 + ds);
    us4 ov = { f2bf(wv.x * hv.x), f2bf(wv.y * hv.y), f2bf(wv.z * hv.z), f2bf(wv.w * hv.w) };
    *reinterpret_cast<us4*>(M + e) = ov;
    return;
  }
  j -= nM4;
  if (j >= nA4) return;
  {
    int e  = j * 4;
    int f  = e % APAD;
    int ii = (e / APAD) & 63;
    int n  = (e / ASLAB) % FDIM;
    int l  = e / (ASLAB * FDIM);
    us4 o = {0, 0, 0, 0};
    if (ii < FDIM) {
#pragma unroll
      for (int k = 0; k < 4; ++k)
        if (f + k < FDIM)
          o[k] = f2bf(alpha[(((size_t)l * FDIM + f + k) * FDIM + ii) * FDIM + n]);
    }
    *reinterpret_cast<us4*>(AT + e) = o;
  }
}

// mfma_f32_32x32x16_bf16 conventions:
//   A[m=lane&31][k=8*(lane>>5)+j]  B[k=8*(lane>>5)+j][col=lane&31]
//   C/D: col=lane&31, row=(reg&3)+8*(reg>>2)+4*(lane>>5)   [HW-verified]
template <bool FINAL>
__global__ __launch_bounds__(256, 2) void layer_k(
    const unsigned short* __restrict__ Bi,   // bf16 [B][40][64] (prev layer / B0b)
    const unsigned short* __restrict__ B0T,  // bf16 [B][64][48]
    const unsigned short* __restrict__ Mt,   // [40][4096] bf16 PRE-SWIZZLED
    const unsigned short* __restrict__ ATt,  // [40][64x56] bf16 zero-padded
    void* __restrict__ outp)                 // bf16 intermediate or f32 final
{
  // Double-buffered 1-n chunks, filled by global_load_lds DMA (linear dest).
  __shared__ unsigned short smM[2][MSLAB];
  __shared__ unsigned short smA[2][ASLAB];

  const int tid  = threadIdx.x;
  const int lane = tid & 63;
  const int w    = tid >> 6;                  // wave 0..3
  const int c    = lane & 31;
  const int h    = lane >> 5;

  // XCD grouping: physical d -> logical L = (d&7)*128 + d>>3; each XCD owns
  // 128 consecutive L = 32 b-groups x all 4 n-splits -> Bi/B0T of a b-group
  // lives in exactly one L2.
  const int L  = (blockIdx.x & 7) * 128 + (blockIdx.x >> 3);
  const int bg = L >> 2;                      // 0..255
  const int ns = L & 3;                       // n-quarter
  const int nBase = ns * NPB;
  const int bb = bg * BPB + w * 2;            // wave's first batch element

  // ---- wave-constant register fragments (loaded once, reused over 10 n) ----
  bf16x8 aBi[2][2][4];
#pragma unroll
  for (int b2 = 0; b2 < 2; ++b2)
#pragma unroll
    for (int it = 0; it < 2; ++it) {
      int row = it * 32 + c; if (row > FDIM - 1) row = FDIM - 1;
#pragma unroll
      for (int ks = 0; ks < 4; ++ks)
        aBi[b2][it][ks] = *reinterpret_cast<const bf16x8*>(
            Bi + ((size_t)(bb + b2) * FDIM + row) * DDIM + ks * 16 + h * 8);
    }
  bf16x8 bT[2][2][3];
#pragma unroll
  for (int b2 = 0; b2 < 2; ++b2)
#pragma unroll
    for (int dt = 0; dt < 2; ++dt)
#pragma unroll
      for (int ks = 0; ks < 3; ++ks)
        bT[b2][dt][ks] = *reinterpret_cast<const bf16x8*>(
            B0T + ((size_t)(bb + b2) * DDIM + dt * 32 + c) * FPAD + ks * 16 + h * 8);

  // ---- DMA one n-slab (M 512 + AT 448 x 16B chunks) into buffer bs ----
  auto dmaChunk = [&](int nl, int bs) {
    const unsigned short* Ms = Mt  + (size_t)(nBase + nl) * MSLAB;
    const unsigned short* As = ATt + (size_t)(nBase + nl) * ASLAB;
#pragma unroll
    for (int r = 0; r < 2; ++r) {
      int k = tid + r * 256;                 // 0..511
      dma16(&smM[bs][k * 8], Ms + k * 8);
    }
    dma16(&smA[bs][tid * 8], As + tid * 8);
    if (tid < 192) dma16(&smA[bs][(tid + 256) * 8], As + (tid + 256) * 8);
  };

  auto compute = [&](int nl, int bs) {
    const int n = nBase + nl;
    const unsigned short* mL = &smM[bs][0];
    const unsigned short* aL = &smA[bs][0];
    // 14 x ds_read_b128; M swizzle folded into prep -> read chunk ^= c&7.
    bf16x8 mb[2][4], at[2][3];
#pragma unroll
    for (int dt = 0; dt < 2; ++dt)
#pragma unroll
      for (int ks = 0; ks < 4; ++ks)
        mb[dt][ks] = *reinterpret_cast<const bf16x8*>(
            mL + (dt * 32 + c) * 64 + (((ks * 2 + h) ^ (c & 7)) * 8));
#pragma unroll
    for (int it = 0; it < 2; ++it)
#pragma unroll
      for (int ks = 0; ks < 3; ++ks)
        at[it][ks] = *reinterpret_cast<const bf16x8*>(
            aL + (it * 32 + c) * APAD + (ks * 2 + h) * 8);

    float pout[2][2] = {{0.f, 0.f}, {0.f, 0.f}};

    // ---- tile pipeline: issue chain(t), THEN combine(t-1). combine(t-1)'s
    // accs retired during this tile's issue -> no scoreboard stall blocking
    // the next MFMAs (in-order issue). Two parity acc sets, static indexing.
    // tile t -> b2 = t&1, dt = (t>>1)&1, it = t>>2.
    f32x16 aC[2], aR[2];
#pragma unroll
    for (int t = 0; t < 8; ++t) {
      const int b2 = t & 1, dt = (t >> 1) & 1, it = t >> 2;
      const int cur = t & 1;
      f32x16 cc = {0,0,0,0,0,0,0,0,0,0,0,0,0,0,0,0};
      f32x16 rr = {0,0,0,0,0,0,0,0,0,0,0,0,0,0,0,0};
#pragma unroll
      for (int ks = 0; ks < 3; ++ks) {
        cc = __builtin_amdgcn_mfma_f32_32x32x16_bf16(aBi[b2][it][ks], mb[dt][ks], cc, 0, 0, 0);
        rr = __builtin_amdgcn_mfma_f32_32x32x16_bf16(at[it][ks], bT[b2][dt][ks], rr, 0, 0, 0);
      }
      cc = __builtin_amdgcn_mfma_f32_32x32x16_bf16(aBi[b2][it][3], mb[dt][3], cc, 0, 0, 0);
      aC[cur] = cc; aR[cur] = rr;
      if (t > 0) {
        const int p   = (t - 1) & 1;
        const int pb2 = (t - 1) & 1, pdt = ((t - 1) >> 1) & 1;
        float t0 = 0.f, t1 = 0.f, t2 = 0.f, t3 = 0.f;
#pragma unroll
        for (int r = 0; r < 4; ++r) {
          t0 += aC[p][r] * aR[p][r];         t1 += aC[p][r + 4] * aR[p][r + 4];
          t2 += aC[p][r + 8] * aR[p][r + 8]; t3 += aC[p][r + 12] * aR[p][r + 12];
        }
        pout[pb2][pdt] += (t0 + t1) + (t2 + t3);
      }
    }
    {   // combine tile 7 (p=1, b2=1, dt=1)
      float t0 = 0.f, t1 = 0.f, t2 = 0.f, t3 = 0.f;
#pragma unroll
      for (int r = 0; r < 4; ++r) {
        t0 += aC[1][r] * aR[1][r];         t1 += aC[1][r + 4] * aR[1][r + 4];
        t2 += aC[1][r + 8] * aR[1][r + 8]; t3 += aC[1][r + 12] * aR[1][r + 12];
      }
      pout[1][1] += (t0 + t1) + (t2 + t3);
    }

#pragma unroll
    for (int b2 = 0; b2 < 2; ++b2) {
      float v0 = pout[b2][0] + __shfl_xor(pout[b2][0], 32, 64);
      float v1 = pout[b2][1] + __shfl_xor(pout[b2][1], 32, 64);
      float val = h ? v1 : v0;
      size_t off = ((size_t)(bb + b2) * FDIM + n) * DDIM + lane;
      if (FINAL) ((float*)outp)[off] = val;
      else       ((unsigned short*)outp)[off] = f2bf(val);
    }
  };

  // ---- main: dbuf 1-n chunks; DMA(n+1) issued before compute(n); barrier
  // (vmcnt(0)+lgkmcnt(0)) drains the DMA under the ~2700cy compute. ----
  dmaChunk(0, 0);
  __syncthreads();
#pragma unroll 1
  for (int cc = 0; cc < NPB; ++cc) {
    const int bs = cc & 1;
    if (cc + 1 < NPB) dmaChunk(cc + 1, bs ^ 1);
    compute(cc, bs);
    __syncthreads();
  }
}

extern "C" void kernel_launch(void* const* d_in, const int* in_sizes, int n_in,
                              void* d_out, int out_size, void* d_ws, size_t ws_size,
                              hipStream_t stream) {
  const float* inputs = (const float*)d_in[0];  // [2048,40,64]
  const float* W      = (const float*)d_in[1];  // [3,40,64,64]
  const float* alpha  = (const float*)d_in[2];  // [3,40,40,40]
  const float* h      = (const float*)d_in[3];  // [3,40,64,1]

  char* ws = (char*)d_ws;
  const size_t S   = (size_t)BATCH * FDIM * DDIM * 2;   // 10.49 MB bf16 buffer
  const size_t ST  = (size_t)BATCH * DDIM * FPAD * 2;   // 12.58 MB B0T
  unsigned short* Bi1 = (unsigned short*)(ws);
  unsigned short* Bi2 = (unsigned short*)(ws + S);
  unsigned short* B0b = (unsigned short*)(ws + 2 * S);
  unsigned short* B0T = (unsigned short*)(ws + 3 * S);
  unsigned short* Mb  = (unsigned short*)(ws + 3 * S + ST);
  unsigned short* ATb = (unsigned short*)(ws + 3 * S + ST + (size_t)LAY * FDIM * MSLAB * 2);

  const int nPrep4 = (LAY * FDIM * MSLAB + LAY * FDIM * ASLAB) / 4;   // 230400
  const int prepBlocks = BATCH + (nPrep4 + 255) / 256;                // 2048 + 900
  prep_all<<<prepBlocks, 256, 0, stream>>>(inputs, W, h, alpha, B0b, B0T, Mb, ATb);

  dim3 grid(BATCH / BPB * NSPL), blk(256);   // 1024 blocks, 4 waves, 8 b each
  const size_t mL = (size_t)FDIM * MSLAB;
  const size_t aL = (size_t)FDIM * ASLAB;
  layer_k<false><<<grid, blk, 0, stream>>>(B0b, B0T, Mb, ATb, Bi1);
  layer_k<false><<<grid, blk, 0, stream>>>(Bi1, B0T, Mb + mL, ATb + aL, Bi2);
  layer_k<true ><<<grid, blk, 0, stream>>>(Bi2, B0T, Mb + 2 * mL, ATb + 2 * aL, d_out);
}

// Round 7
// 241.908 us; speedup vs baseline: 3.5527x; 3.5527x over previous
//
#include <hip/hip_runtime.h>

// GeneralizedInteractionNet on MI355X (gfx950). R16: alternating named acc
// pairs (deferred combine, in-budget) + coalesced alpha prep.
//
// Per layer:  M[n,D,d] = W[n,D,d]*h[n,d]
//   GEMM1: C[b,i,D] = sum_d Bi[b,i,d] * M[n,D,d]
//   GEMM2: R[b,i,D] = sum_f AT[n,i,f] * B0T[b,D,f]^T
//   out[b,n,D] = sum_i C[b,i,D]*R[b,i,D]
// i padded 40->64 (2 row tiles of 32); f padded 40->48 (3 K-steps of 16).
//
// History:
//  R9 263us (MfmaUtil 39) / R10 361us (reg-dbuf sunk) / R11 261us (4-chain
//  interleave = noise) / R12 235us (LDS staging + XCD grouping, 47%) /
//  R13 908us (launch_bounds(256,4) spill) / R14 240us (= R12; acc-zero kill
//  + DMA staging neutral; VALU 26% unchanged) /
//  R15 859us FAILED: aC[2]/aR[2] + live cc/rr = 3 acc sets = ~280 regs ->
//    spill (WRITE 133MB, FETCH 705MB). Stall theory untested.
//  R16: same theory, in budget. Tile t issues into set X while ONLY set Y
//    (t-1) is held; combine(t-1) sits after issue(t) in program order so the
//    matrix pipe keeps issuing during the combine's scoreboard wait. Peak
//    live acc = 64 (R11-proven). z16 dropped (R14: zero-init off critical
//    path). Prep: alpha read COALESCED (float4 linear), bf16 stores
//    scattered (stores don't stall); pad zeros via one hipMemsetAsync.
//  Tripwire: WRITE_SIZE must stay ~10MB / VGPR ~120. If spilled -> revert
//    acc scheme, keep prep. If clean but MfmaUtil flat ~47% -> stall theory
//    dead, move to wave role-split.

typedef __bf16 bf16x8 __attribute__((ext_vector_type(8)));
typedef float  f32x16 __attribute__((ext_vector_type(16)));
typedef unsigned short us4 __attribute__((ext_vector_type(4)));

constexpr int BATCH = 2048;
constexpr int FDIM  = 40;
constexpr int DDIM  = 64;
constexpr int LAY   = 3;
constexpr int FPAD  = 48;   // f padding for B0T (3 K-steps of 16)
constexpr int APAD  = 56;   // AT row stride in ushorts (112B -> 4-way max)
constexpr int NSPL  = 4;    // n-loop split across 4 blocks
constexpr int NPB   = FDIM / NSPL;    // 10 n per block
constexpr int BPB   = 8;    // b per block (4 waves x b2=2)
constexpr int MSLAB = DDIM * DDIM;    // 4096 ushort per n (8 KB)
constexpr int ASLAB = DDIM * APAD;    // 3584 ushort per n (7 KB)

__device__ __forceinline__ unsigned short f2bf(float f) {
  union { float f; unsigned u; } v; v.f = f;
  unsigned r = v.u + 0x7fff + ((v.u >> 16) & 1);   // round-to-nearest-even
  return (unsigned short)(r >> 16);
}

__device__ __forceinline__ void dma16(unsigned short* lds, const unsigned short* g) {
  __builtin_amdgcn_global_load_lds(
      (const __attribute__((address_space(1))) unsigned int*)g,
      (__attribute__((address_space(3))) unsigned int*)lds, 16, 0, 0);
}

// Single prep launch, role by blockIdx.x:
//  blocks [0, BATCH):  B0b[b,f,d] = bf16(inputs); B0T[b,d,f48] via LDS transpose
//  blocks [BATCH, ..): Mswz (pre-swizzled W*h); AT[l,n,i,f] = alpha[l,f,i,n]
//    (alpha read LINEARLY -- n fastest -- so loads coalesce; stores scatter).
//    AT pad zeros pre-set by hipMemsetAsync.
__global__ __launch_bounds__(256) void prep_all(
    const float* __restrict__ inputs, const float* __restrict__ W,
    const float* __restrict__ h, const float* __restrict__ alpha,
    unsigned short* __restrict__ B0b, unsigned short* __restrict__ B0T,
    unsigned short* __restrict__ M, unsigned short* __restrict__ AT) {
  __shared__ float lds[FDIM][DDIM + 1];
  if (blockIdx.x < BATCH) {
    const int b = blockIdx.x;
    const float* src = inputs + (size_t)b * FDIM * DDIM;
    for (int cch = threadIdx.x; cch < FDIM * DDIM / 4; cch += 256) {
      float4 v = reinterpret_cast<const float4*>(src)[cch];
      int e = cch * 4;
      int f = e >> 6, d = e & 63;
      lds[f][d] = v.x; lds[f][d + 1] = v.y; lds[f][d + 2] = v.z; lds[f][d + 3] = v.w;
      us4 o = { f2bf(v.x), f2bf(v.y), f2bf(v.z), f2bf(v.w) };
      reinterpret_cast<us4*>(B0b + (size_t)b * FDIM * DDIM)[cch] = o;
    }
    __syncthreads();
    for (int cch = threadIdx.x; cch < DDIM * FPAD / 4; cch += 256) {
      int f4 = cch % (FPAD / 4);
      int d  = cch / (FPAD / 4);
      us4 o = {0, 0, 0, 0};
      if (f4 < FDIM / 4) {
        int f = f4 * 4;
        o[0] = f2bf(lds[f][d]);     o[1] = f2bf(lds[f + 1][d]);
        o[2] = f2bf(lds[f + 2][d]); o[3] = f2bf(lds[f + 3][d]);
      }
      reinterpret_cast<us4*>(B0T + (size_t)b * DDIM * FPAD)[cch] = o;
    }
    return;
  }
  int j = (blockIdx.x - BATCH) * 256 + threadIdx.x;
  const int nM4  = LAY * FDIM * MSLAB / 4;          // 122880
  const int nAl4 = LAY * FDIM * FDIM * FDIM / 4;    // 48000 (alpha elems /4)
  if (j < nM4) {
    // Mswz linear pos e = row*64 + jc*8 + o holds M[ln][row][(jc^(row&7))*8+o]
    // so the layer's swizzled ds_read (chunk ^= c&7) lands on natural data.
    int e   = j * 4;
    int ln  = e >> 12;
    int row = (e >> 6) & 63;
    int jc  = (e >> 3) & 7;
    int o   = e & 7;                      // 0 or 4
    int ds  = ((jc ^ (row & 7)) << 3) + o;
    float4 wv = *reinterpret_cast<const float4*>(W + ((size_t)ln * 64 + row) * 64 + ds);
    float4 hv = *reinterpret_cast<const float4*>(h + (size_t)ln * 64 + ds);
    us4 ov = { f2bf(wv.x * hv.x), f2bf(wv.y * hv.y), f2bf(wv.z * hv.z), f2bf(wv.w * hv.w) };
    *reinterpret_cast<us4*>(M + e) = ov;
    return;
  }
  j -= nM4;
  if (j >= nAl4) return;
  {
    // alpha[l][f][i][n], n fastest. e = linear elem index -> coalesced float4.
    int e = j * 4;
    int n = e % FDIM;                 // aligned: 40 % 4 == 0
    int i = (e / FDIM) % FDIM;
    int f = (e / (FDIM * FDIM)) % FDIM;
    int l = e / (FDIM * FDIM * FDIM);
    float4 v = *reinterpret_cast<const float4*>(alpha + e);
    unsigned short* dst = AT + ((size_t)l * FDIM) * ASLAB + (size_t)i * APAD + f;
#pragma unroll
    for (int k = 0; k < 4; ++k) {
      float vk = (k == 0) ? v.x : (k == 1) ? v.y : (k == 2) ? v.z : v.w;
      dst[(size_t)(n + k) * ASLAB] = f2bf(vk);
    }
  }
}

// mfma_f32_32x32x16_bf16 conventions:
//   A[m=lane&31][k=8*(lane>>5)+j]  B[k=8*(lane>>5)+j][col=lane&31]
//   C/D: col=lane&31, row=(reg&3)+8*(reg>>2)+4*(lane>>5)   [HW-verified]
template <bool FINAL>
__global__ __launch_bounds__(256, 2) void layer_k(
    const unsigned short* __restrict__ Bi,   // bf16 [B][40][64] (prev layer / B0b)
    const unsigned short* __restrict__ B0T,  // bf16 [B][64][48]
    const unsigned short* __restrict__ Mt,   // [40][4096] bf16 PRE-SWIZZLED
    const unsigned short* __restrict__ ATt,  // [40][64x56] bf16 zero-padded
    void* __restrict__ outp)                 // bf16 intermediate or f32 final
{
  // Double-buffered 1-n chunks, filled by global_load_lds DMA (linear dest).
  __shared__ unsigned short smM[2][MSLAB];
  __shared__ unsigned short smA[2][ASLAB];

  const int tid  = threadIdx.x;
  const int lane = tid & 63;
  const int w    = tid >> 6;                  // wave 0..3
  const int c    = lane & 31;
  const int h    = lane >> 5;

  // XCD grouping: physical d -> logical L = (d&7)*128 + d>>3; each XCD owns
  // 128 consecutive L = 32 b-groups x all 4 n-splits -> Bi/B0T of a b-group
  // lives in exactly one L2.
  const int L  = (blockIdx.x & 7) * 128 + (blockIdx.x >> 3);
  const int bg = L >> 2;                      // 0..255
  const int ns = L & 3;                       // n-quarter
  const int nBase = ns * NPB;
  const int bb = bg * BPB + w * 2;            // wave's first batch element

  // ---- wave-constant register fragments (loaded once, reused over 10 n) ----
  bf16x8 aBi[2][2][4];
#pragma unroll
  for (int b2 = 0; b2 < 2; ++b2)
#pragma unroll
    for (int it = 0; it < 2; ++it) {
      int row = it * 32 + c; if (row > FDIM - 1) row = FDIM - 1;
#pragma unroll
      for (int ks = 0; ks < 4; ++ks)
        aBi[b2][it][ks] = *reinterpret_cast<const bf16x8*>(
            Bi + ((size_t)(bb + b2) * FDIM + row) * DDIM + ks * 16 + h * 8);
    }
  bf16x8 bT[2][2][3];
#pragma unroll
  for (int b2 = 0; b2 < 2; ++b2)
#pragma unroll
    for (int dt = 0; dt < 2; ++dt)
#pragma unroll
      for (int ks = 0; ks < 3; ++ks)
        bT[b2][dt][ks] = *reinterpret_cast<const bf16x8*>(
            B0T + ((size_t)(bb + b2) * DDIM + dt * 32 + c) * FPAD + ks * 16 + h * 8);

  // ---- DMA one n-slab (M 512 + AT 448 x 16B chunks) into buffer bs ----
  auto dmaChunk = [&](int nl, int bs) {
    const unsigned short* Ms = Mt  + (size_t)(nBase + nl) * MSLAB;
    const unsigned short* As = ATt + (size_t)(nBase + nl) * ASLAB;
#pragma unroll
    for (int r = 0; r < 2; ++r) {
      int k = tid + r * 256;                 // 0..511
      dma16(&smM[bs][k * 8], Ms + k * 8);
    }
    dma16(&smA[bs][tid * 8], As + tid * 8);
    if (tid < 192) dma16(&smA[bs][(tid + 256) * 8], As + (tid + 256) * 8);
  };

  auto compute = [&](int nl, int bs) {
    const int n = nBase + nl;
    const unsigned short* mL = &smM[bs][0];
    const unsigned short* aL = &smA[bs][0];
    // 14 x ds_read_b128; M swizzle folded into prep -> read chunk ^= c&7.
    bf16x8 mb[2][4], at[2][3];
#pragma unroll
    for (int dt = 0; dt < 2; ++dt)
#pragma unroll
      for (int ks = 0; ks < 4; ++ks)
        mb[dt][ks] = *reinterpret_cast<const bf16x8*>(
            mL + (dt * 32 + c) * 64 + (((ks * 2 + h) ^ (c & 7)) * 8));
#pragma unroll
    for (int it = 0; it < 2; ++it)
#pragma unroll
      for (int ks = 0; ks < 3; ++ks)
        at[it][ks] = *reinterpret_cast<const bf16x8*>(
            aL + (it * 32 + c) * APAD + (ks * 2 + h) * 8);

    float pout[2][2] = {{0.f, 0.f}, {0.f, 0.f}};

    // ---- alternating named acc pairs: issue(t) into X, then combine(t-1)
    // from Y. Peak live acc = 64 (2 sets), operands never change. In-order
    // issue keeps the matrix pipe fed while the combine waits on Y's regs
    // (long retired). tile t: b2 = t&1, dt = (t>>1)&1, it = t>>2.
    f32x16 cA, rA, cB, rB;

    auto issueT = [&](int b2, int dt, int it, f32x16& cc, f32x16& rr) {
      f32x16 c0 = {0,0,0,0,0,0,0,0,0,0,0,0,0,0,0,0};
      f32x16 r0 = {0,0,0,0,0,0,0,0,0,0,0,0,0,0,0,0};
#pragma unroll
      for (int ks = 0; ks < 3; ++ks) {
        c0 = __builtin_amdgcn_mfma_f32_32x32x16_bf16(aBi[b2][it][ks], mb[dt][ks], c0, 0, 0, 0);
        r0 = __builtin_amdgcn_mfma_f32_32x32x16_bf16(at[it][ks], bT[b2][dt][ks], r0, 0, 0, 0);
      }
      cc = __builtin_amdgcn_mfma_f32_32x32x16_bf16(aBi[b2][it][3], mb[dt][3], c0, 0, 0, 0);
      rr = r0;
    };
    auto combineT = [&](int b2, int dt, const f32x16& cc, const f32x16& rr) {
      float t0 = 0.f, t1 = 0.f, t2 = 0.f, t3 = 0.f;
#pragma unroll
      for (int r = 0; r < 4; ++r) {
        t0 += cc[r] * rr[r];         t1 += cc[r + 4] * rr[r + 4];
        t2 += cc[r + 8] * rr[r + 8]; t3 += cc[r + 12] * rr[r + 12];
      }
      pout[b2][dt] += (t0 + t1) + (t2 + t3);
    };

    issueT(0, 0, 0, cA, rA);                        // t0 -> A
    issueT(1, 0, 0, cB, rB); combineT(0, 0, cA, rA); // t1 -> B, comb t0
    issueT(0, 1, 0, cA, rA); combineT(1, 0, cB, rB); // t2 -> A, comb t1
    issueT(1, 1, 0, cB, rB); combineT(0, 1, cA, rA); // t3 -> B, comb t2
    issueT(0, 0, 1, cA, rA); combineT(1, 1, cB, rB); // t4 -> A, comb t3
    issueT(1, 0, 1, cB, rB); combineT(0, 0, cA, rA); // t5 -> B, comb t4
    issueT(0, 1, 1, cA, rA); combineT(1, 0, cB, rB); // t6 -> A, comb t5
    issueT(1, 1, 1, cB, rB); combineT(0, 1, cA, rA); // t7 -> B, comb t6
    combineT(1, 1, cB, rB);                          // comb t7

#pragma unroll
    for (int b2 = 0; b2 < 2; ++b2) {
      float v0 = pout[b2][0] + __shfl_xor(pout[b2][0], 32, 64);
      float v1 = pout[b2][1] + __shfl_xor(pout[b2][1], 32, 64);
      float val = h ? v1 : v0;
      size_t off = ((size_t)(bb + b2) * FDIM + n) * DDIM + lane;
      if (FINAL) ((float*)outp)[off] = val;
      else       ((unsigned short*)outp)[off] = f2bf(val);
    }
  };

  // ---- main: dbuf 1-n chunks; DMA(n+1) issued before compute(n); barrier
  // (vmcnt(0)+lgkmcnt(0)) drains the DMA under the ~2700cy compute. ----
  dmaChunk(0, 0);
  __syncthreads();
#pragma unroll 1
  for (int cc = 0; cc < NPB; ++cc) {
    const int bs = cc & 1;
    if (cc + 1 < NPB) dmaChunk(cc + 1, bs ^ 1);
    compute(cc, bs);
    __syncthreads();
  }
}

extern "C" void kernel_launch(void* const* d_in, const int* in_sizes, int n_in,
                              void* d_out, int out_size, void* d_ws, size_t ws_size,
                              hipStream_t stream) {
  const float* inputs = (const float*)d_in[0];  // [2048,40,64]
  const float* W      = (const float*)d_in[1];  // [3,40,64,64]
  const float* alpha  = (const float*)d_in[2];  // [3,40,40,40]
  const float* h      = (const float*)d_in[3];  // [3,40,64,1]

  char* ws = (char*)d_ws;
  const size_t S   = (size_t)BATCH * FDIM * DDIM * 2;   // 10.49 MB bf16 buffer
  const size_t ST  = (size_t)BATCH * DDIM * FPAD * 2;   // 12.58 MB B0T
  unsigned short* Bi1 = (unsigned short*)(ws);
  unsigned short* Bi2 = (unsigned short*)(ws + S);
  unsigned short* B0b = (unsigned short*)(ws + 2 * S);
  unsigned short* B0T = (unsigned short*)(ws + 3 * S);
  unsigned short* Mb  = (unsigned short*)(ws + 3 * S + ST);
  unsigned short* ATb = (unsigned short*)(ws + 3 * S + ST + (size_t)LAY * FDIM * MSLAB * 2);

  // AT pad zeros (rows i>=40 never written; f in [40,56) never written).
  hipMemsetAsync(ATb, 0, (size_t)LAY * FDIM * ASLAB * 2, stream);

  const int nPrep4 = (LAY * FDIM * MSLAB + LAY * FDIM * FDIM * FDIM) / 4;  // 170880
  const int prepBlocks = BATCH + (nPrep4 + 255) / 256;                     // 2048 + 668
  prep_all<<<prepBlocks, 256, 0, stream>>>(inputs, W, h, alpha, B0b, B0T, Mb, ATb);

  dim3 grid(BATCH / BPB * NSPL), blk(256);   // 1024 blocks, 4 waves, 8 b each
  const size_t mL = (size_t)FDIM * MSLAB;
  const size_t aL = (size_t)FDIM * ASLAB;
  layer_k<false><<<grid, blk, 0, stream>>>(B0b, B0T, Mb, ATb, Bi1);
  layer_k<false><<<grid, blk, 0, stream>>>(Bi1, B0T, Mb + mL, ATb + aL, Bi2);
  layer_k<true ><<<grid, blk, 0, stream>>>(Bi2, B0T, Mb + 2 * mL, ATb + 2 * aL, d_out);
}